// Round 1
// baseline (356.680 us; speedup 1.0000x reference)
//
#include <hip/hip_runtime.h>
#include <hip/hip_bf16.h>
#include <stdint.h>

#define N_ROWS 8192
#define DIM 1024
#define NUM_CLS 200

typedef __attribute__((ext_vector_type(8))) short bf16x8;
typedef __attribute__((ext_vector_type(4))) float f32x4;

__device__ __forceinline__ ushort f2bf(float f) {
    __hip_bfloat16 h = __float2bfloat16(f);
    return *reinterpret_cast<ushort*>(&h);
}

// ---------- Kernel 1: row L2-normalize, cast to bf16 ----------
__global__ __launch_bounds__(256) void normalize_kernel(const float* __restrict__ z,
                                                        ushort* __restrict__ zn) {
    const int row = blockIdx.x;
    const int t = threadIdx.x;
    const float4 v = reinterpret_cast<const float4*>(z + (size_t)row * DIM)[t];
    float ss = v.x * v.x + v.y * v.y + v.z * v.z + v.w * v.w;
    #pragma unroll
    for (int off = 1; off < 64; off <<= 1) ss += __shfl_xor(ss, off);
    __shared__ float wsum[4];
    if ((t & 63) == 0) wsum[t >> 6] = ss;
    __syncthreads();
    const float tot = wsum[0] + wsum[1] + wsum[2] + wsum[3];
    const float inv = 1.0f / fmaxf(sqrtf(tot), 1e-8f);
    ushort4 o;
    o.x = f2bf(v.x * inv);
    o.y = f2bf(v.y * inv);
    o.z = f2bf(v.z * inv);
    o.w = f2bf(v.w * inv);
    reinterpret_cast<ushort4*>(zn + (size_t)row * DIM)[t] = o;
}

// ---------- Kernel 2: fused Gram + exp + masked row sums ----------
// S = Zn * Zn^T, tile 128x128, BK=64, 4 waves (2x2), each wave 64x64 out.
__global__ __launch_bounds__(256) void gram_kernel(const ushort* __restrict__ zn,
                                                   const int* __restrict__ labels,
                                                   float* __restrict__ row_same,
                                                   float* __restrict__ row_diff) {
    __shared__ ushort sA[128 * 64];
    __shared__ ushort sB[128 * 64];
    __shared__ int labR[128], labC[128];

    const int bi = blockIdx.x, bj = blockIdx.y;
    const int r0 = bi * 128, c0 = bj * 128;
    const int t = threadIdx.x;
    const int lane = t & 63, wv = t >> 6;
    const int wr = wv >> 1, wc = wv & 1;

    if (t < 128) labR[t] = labels[r0 + t];
    else labC[t - 128] = labels[c0 + (t - 128)];

    f32x4 acc[4][4];
    #pragma unroll
    for (int m = 0; m < 4; m++)
        #pragma unroll
        for (int n = 0; n < 4; n++) acc[m][n] = (f32x4){0.f, 0.f, 0.f, 0.f};

    const int lrow = lane >> 3;  // 0..7 rows within a 1KB stage chunk
    const int lcol = lane & 7;   // 0..7 chunks of 8 bf16 (16B)

    for (int kt = 0; kt < DIM; kt += 64) {
        // stage A and B tiles: each wave-call covers 8 rows x 64 cols (1KB)
        #pragma unroll
        for (int c = 0; c < 4; c++) {
            const int rowT = wv * 32 + c * 8 + lrow;
            const ushort* gA = zn + (size_t)(r0 + rowT) * DIM + kt + lcol * 8;
            __builtin_amdgcn_global_load_lds(
                (const __attribute__((address_space(1))) uint32_t*)gA,
                (__attribute__((address_space(3))) uint32_t*)&sA[rowT * 64 + lcol * 8],
                16, 0, 0);
            const ushort* gB = zn + (size_t)(c0 + rowT) * DIM + kt + lcol * 8;
            __builtin_amdgcn_global_load_lds(
                (const __attribute__((address_space(1))) uint32_t*)gB,
                (__attribute__((address_space(3))) uint32_t*)&sB[rowT * 64 + lcol * 8],
                16, 0, 0);
        }
        __syncthreads();
        #pragma unroll
        for (int ks = 0; ks < 2; ks++) {
            const int kof = ks * 32 + (lane >> 4) * 8;
            bf16x8 af[4], bfr[4];
            #pragma unroll
            for (int m = 0; m < 4; m++)
                af[m] = *reinterpret_cast<const bf16x8*>(
                    &sA[(wr * 64 + m * 16 + (lane & 15)) * 64 + kof]);
            #pragma unroll
            for (int n = 0; n < 4; n++)
                bfr[n] = *reinterpret_cast<const bf16x8*>(
                    &sB[(wc * 64 + n * 16 + (lane & 15)) * 64 + kof]);
            #pragma unroll
            for (int m = 0; m < 4; m++)
                #pragma unroll
                for (int n = 0; n < 4; n++)
                    acc[m][n] = __builtin_amdgcn_mfma_f32_16x16x32_bf16(
                        af[m], bfr[n], acc[m][n], 0, 0, 0);
        }
        __syncthreads();
    }

    // Epilogue: E = exp(S); accumulate masked row sums.
    // C/D layout: col = lane&15, row = (lane>>4)*4 + q   [m89 verified]
    float rs[4][4], rd[4][4];
    #pragma unroll
    for (int m = 0; m < 4; m++)
        #pragma unroll
        for (int q = 0; q < 4; q++) { rs[m][q] = 0.f; rd[m][q] = 0.f; }

    #pragma unroll
    for (int n = 0; n < 4; n++) {
        const int jj = wc * 64 + n * 16 + (lane & 15);
        const int j = c0 + jj;
        const int lj = labC[jj];
        #pragma unroll
        for (int m = 0; m < 4; m++) {
            #pragma unroll
            for (int q = 0; q < 4; q++) {
                const int ii = wr * 64 + m * 16 + (lane >> 4) * 4 + q;
                const int i = r0 + ii;
                const float e = __expf(acc[m][n][q]);
                if (i != j) {
                    if (labR[ii] == lj) rs[m][q] += e;
                    else                rd[m][q] += e;
                }
            }
        }
    }

    // Reduce across the 16 lanes sharing the same output row, then atomicAdd.
    #pragma unroll
    for (int m = 0; m < 4; m++) {
        #pragma unroll
        for (int q = 0; q < 4; q++) {
            float vs = rs[m][q], vd = rd[m][q];
            #pragma unroll
            for (int off = 1; off < 16; off <<= 1) {
                vs += __shfl_xor(vs, off);
                vd += __shfl_xor(vd, off);
            }
            if ((lane & 15) == 0) {
                const int i = r0 + wr * 64 + m * 16 + (lane >> 4) * 4 + q;
                atomicAdd(&row_same[i], vs);
                atomicAdd(&row_diff[i], vd);
            }
        }
    }
}

// ---------- Kernel 3: segment sums over classes + final scalar ----------
__global__ __launch_bounds__(256) void finalize_kernel(const int* __restrict__ labels,
                                                       const float* __restrict__ row_same,
                                                       const float* __restrict__ row_diff,
                                                       float* __restrict__ out) {
    __shared__ float ss[NUM_CLS], sd[NUM_CLS];
    __shared__ int cnt[NUM_CLS];
    const int t = threadIdx.x;
    for (int c = t; c < NUM_CLS; c += 256) { ss[c] = 0.f; sd[c] = 0.f; cnt[c] = 0; }
    __syncthreads();
    for (int r = t; r < N_ROWS; r += 256) {
        const int l = labels[r];
        atomicAdd(&ss[l], row_same[r]);
        atomicAdd(&sd[l], row_diff[r]);
        atomicAdd(&cnt[l], 1);
    }
    __syncthreads();
    float p = 0.f;
    for (int c = t; c < NUM_CLS; c += 256)
        if (cnt[c] > 0) p += logf(ss[c] / sd[c]);
    #pragma unroll
    for (int off = 1; off < 64; off <<= 1) p += __shfl_xor(p, off);
    __shared__ float wsum[4];
    if ((t & 63) == 0) wsum[t >> 6] = p;
    __syncthreads();
    if (t == 0) out[0] = (wsum[0] + wsum[1] + wsum[2] + wsum[3]) / 128.0f;
}

extern "C" void kernel_launch(void* const* d_in, const int* in_sizes, int n_in,
                              void* d_out, int out_size, void* d_ws, size_t ws_size,
                              hipStream_t stream) {
    const float* z = (const float*)d_in[1];       // semantic_embeddings
    const int* labels = (const int*)d_in[3];      // labels (int32 per harness)

    ushort* zn = (ushort*)d_ws;                                   // 16 MB bf16
    float* row_same = (float*)((char*)d_ws + (size_t)N_ROWS * DIM * 2);
    float* row_diff = row_same + N_ROWS;

    hipMemsetAsync(row_same, 0, 2 * N_ROWS * sizeof(float), stream);

    normalize_kernel<<<N_ROWS, 256, 0, stream>>>(z, zn);

    dim3 grid(N_ROWS / 128, N_ROWS / 128);
    gram_kernel<<<grid, 256, 0, stream>>>(zn, labels, row_same, row_diff);

    finalize_kernel<<<1, 256, 0, stream>>>(labels, row_same, row_diff, (float*)d_out);
}

// Round 2
// 310.433 us; speedup vs baseline: 1.1490x; 1.1490x over previous
//
#include <hip/hip_runtime.h>
#include <hip/hip_bf16.h>
#include <stdint.h>

#define N_ROWS 8192
#define DIM 1024
#define NUM_CLS 200
#define NT 64              // 128-row tiles per dimension
#define NTILES (NT * (NT + 1) / 2)   // 2080 upper-triangular tiles

typedef __attribute__((ext_vector_type(8))) short bf16x8;
typedef __attribute__((ext_vector_type(4))) float f32x4;

__device__ __forceinline__ ushort f2bf(float f) {
    __hip_bfloat16 h = __float2bfloat16(f);
    return *reinterpret_cast<ushort*>(&h);
}

// ---------- Kernel 1: row L2-normalize, cast to bf16 ----------
__global__ __launch_bounds__(256) void normalize_kernel(const float* __restrict__ z,
                                                        ushort* __restrict__ zn) {
    const int row = blockIdx.x;
    const int t = threadIdx.x;
    const float4 v = reinterpret_cast<const float4*>(z + (size_t)row * DIM)[t];
    float ss = v.x * v.x + v.y * v.y + v.z * v.z + v.w * v.w;
    #pragma unroll
    for (int off = 1; off < 64; off <<= 1) ss += __shfl_xor(ss, off);
    __shared__ float wsum[4];
    if ((t & 63) == 0) wsum[t >> 6] = ss;
    __syncthreads();
    const float tot = wsum[0] + wsum[1] + wsum[2] + wsum[3];
    const float inv = 1.0f / fmaxf(sqrtf(tot), 1e-8f);
    ushort4 o;
    o.x = f2bf(v.x * inv);
    o.y = f2bf(v.y * inv);
    o.z = f2bf(v.z * inv);
    o.w = f2bf(v.w * inv);
    reinterpret_cast<ushort4*>(zn + (size_t)row * DIM)[t] = o;
}

// ---------- Kernel 2: fused Gram + exp + masked row sums, symmetric ----------
// Only upper-triangular tiles (bi <= bj). Off-diagonal tiles contribute
// both row sums (rows r0..r0+127) and, via symmetry, column sums
// (rows c0..c0+127).
__global__ __launch_bounds__(256) void gram_kernel(const ushort* __restrict__ zn,
                                                   const int* __restrict__ labels,
                                                   float* __restrict__ row_same,
                                                   float* __restrict__ row_diff) {
    __shared__ ushort sA[128 * 64];
    __shared__ ushort sB[128 * 64];
    __shared__ int labR[128], labC[128];

    // triangular decode: blockIdx.x -> (bi, bj), bi <= bj
    int rem = blockIdx.x, bi = 0, rowlen = NT;
    while (rem >= rowlen) { rem -= rowlen; ++bi; --rowlen; }
    const int bj = bi + rem;
    const bool diag = (bi == bj);

    const int r0 = bi * 128, c0 = bj * 128;
    const int t = threadIdx.x;
    const int lane = t & 63, wv = t >> 6;
    const int wr = wv >> 1, wc = wv & 1;

    if (t < 128) labR[t] = labels[r0 + t];
    else labC[t - 128] = labels[c0 + (t - 128)];

    f32x4 acc[4][4];
    #pragma unroll
    for (int m = 0; m < 4; m++)
        #pragma unroll
        for (int n = 0; n < 4; n++) acc[m][n] = (f32x4){0.f, 0.f, 0.f, 0.f};

    const int lrow = lane >> 3;  // 0..7 rows within a 1KB stage chunk
    const int lcol = lane & 7;   // 0..7 chunks of 8 bf16 (16B)

    for (int kt = 0; kt < DIM; kt += 64) {
        #pragma unroll
        for (int c = 0; c < 4; c++) {
            const int rowT = wv * 32 + c * 8 + lrow;
            const ushort* gA = zn + (size_t)(r0 + rowT) * DIM + kt + lcol * 8;
            __builtin_amdgcn_global_load_lds(
                (const __attribute__((address_space(1))) uint32_t*)gA,
                (__attribute__((address_space(3))) uint32_t*)&sA[rowT * 64 + lcol * 8],
                16, 0, 0);
            const ushort* gB = zn + (size_t)(c0 + rowT) * DIM + kt + lcol * 8;
            __builtin_amdgcn_global_load_lds(
                (const __attribute__((address_space(1))) uint32_t*)gB,
                (__attribute__((address_space(3))) uint32_t*)&sB[rowT * 64 + lcol * 8],
                16, 0, 0);
        }
        __syncthreads();
        #pragma unroll
        for (int ks = 0; ks < 2; ks++) {
            const int kof = ks * 32 + (lane >> 4) * 8;
            bf16x8 af[4], bfr[4];
            #pragma unroll
            for (int m = 0; m < 4; m++)
                af[m] = *reinterpret_cast<const bf16x8*>(
                    &sA[(wr * 64 + m * 16 + (lane & 15)) * 64 + kof]);
            #pragma unroll
            for (int n = 0; n < 4; n++)
                bfr[n] = *reinterpret_cast<const bf16x8*>(
                    &sB[(wc * 64 + n * 16 + (lane & 15)) * 64 + kof]);
            #pragma unroll
            for (int m = 0; m < 4; m++)
                #pragma unroll
                for (int n = 0; n < 4; n++)
                    acc[m][n] = __builtin_amdgcn_mfma_f32_16x16x32_bf16(
                        af[m], bfr[n], acc[m][n], 0, 0, 0);
        }
        __syncthreads();
    }

    // Epilogue. C/D layout: col = lane&15, row = (lane>>4)*4 + q  [m89]
    float rs[4][4], rd[4][4];   // per (m,q): row partial sums
    float cs[4], cd[4];         // per n: column partial sums (off-diag only)
    #pragma unroll
    for (int m = 0; m < 4; m++)
        #pragma unroll
        for (int q = 0; q < 4; q++) { rs[m][q] = 0.f; rd[m][q] = 0.f; }

    #pragma unroll
    for (int n = 0; n < 4; n++) {
        const int jj = wc * 64 + n * 16 + (lane & 15);
        const int j = c0 + jj;
        const int lj = labC[jj];
        float csn = 0.f, cdn = 0.f;
        #pragma unroll
        for (int m = 0; m < 4; m++) {
            #pragma unroll
            for (int q = 0; q < 4; q++) {
                const int ii = wr * 64 + m * 16 + (lane >> 4) * 4 + q;
                const float e = __expf(acc[m][n][q]);
                const bool same = (labR[ii] == lj);
                if (diag) {
                    if (r0 + ii != j) {
                        if (same) rs[m][q] += e; else rd[m][q] += e;
                    }
                } else {
                    if (same) { rs[m][q] += e; csn += e; }
                    else      { rd[m][q] += e; cdn += e; }
                }
            }
        }
        cs[n] = csn; cd[n] = cdn;
    }

    // Row reduction: across the 16 lanes sharing an output row.
    #pragma unroll
    for (int m = 0; m < 4; m++) {
        #pragma unroll
        for (int q = 0; q < 4; q++) {
            float vs = rs[m][q], vd = rd[m][q];
            #pragma unroll
            for (int off = 1; off < 16; off <<= 1) {
                vs += __shfl_xor(vs, off);
                vd += __shfl_xor(vd, off);
            }
            if ((lane & 15) == 0) {
                const int i = r0 + wr * 64 + m * 16 + (lane >> 4) * 4 + q;
                atomicAdd(&row_same[i], vs);
                atomicAdd(&row_diff[i], vd);
            }
        }
    }

    // Column reduction (symmetry contribution), off-diagonal tiles only:
    // sum across the four lane>>4 groups, then lanes 0-15 hold col totals.
    if (!diag) {
        #pragma unroll
        for (int n = 0; n < 4; n++) {
            float vs = cs[n], vd = cd[n];
            vs += __shfl_xor(vs, 16); vd += __shfl_xor(vd, 16);
            vs += __shfl_xor(vs, 32); vd += __shfl_xor(vd, 32);
            if (lane < 16) {
                const int j = c0 + wc * 64 + n * 16 + lane;
                atomicAdd(&row_same[j], vs);
                atomicAdd(&row_diff[j], vd);
            }
        }
    }
}

// ---------- Kernel 3a: per-block class partial sums ----------
__global__ __launch_bounds__(256) void class_sum_kernel(const int* __restrict__ labels,
                                                        const float* __restrict__ row_same,
                                                        const float* __restrict__ row_diff,
                                                        float* __restrict__ cls_same,
                                                        float* __restrict__ cls_diff,
                                                        int* __restrict__ cls_cnt) {
    __shared__ float ls[NUM_CLS], ld_[NUM_CLS];
    __shared__ int lc[NUM_CLS];
    const int t = threadIdx.x;
    for (int c = t; c < NUM_CLS; c += 256) { ls[c] = 0.f; ld_[c] = 0.f; lc[c] = 0; }
    __syncthreads();
    const int r = blockIdx.x * 256 + t;
    if (r < N_ROWS) {
        const int l = labels[r];
        atomicAdd(&ls[l], row_same[r]);
        atomicAdd(&ld_[l], row_diff[r]);
        atomicAdd(&lc[l], 1);
    }
    __syncthreads();
    for (int c = t; c < NUM_CLS; c += 256) {
        if (lc[c] > 0) {
            atomicAdd(&cls_same[c], ls[c]);
            atomicAdd(&cls_diff[c], ld_[c]);
            atomicAdd(&cls_cnt[c], lc[c]);
        }
    }
}

// ---------- Kernel 3b: final scalar ----------
__global__ __launch_bounds__(256) void final_kernel(const float* __restrict__ cls_same,
                                                    const float* __restrict__ cls_diff,
                                                    const int* __restrict__ cls_cnt,
                                                    float* __restrict__ out) {
    const int t = threadIdx.x;
    float p = 0.f;
    if (t < NUM_CLS && cls_cnt[t] > 0) p = logf(cls_same[t] / cls_diff[t]);
    #pragma unroll
    for (int off = 1; off < 64; off <<= 1) p += __shfl_xor(p, off);
    __shared__ float wsum[4];
    if ((t & 63) == 0) wsum[t >> 6] = p;
    __syncthreads();
    if (t == 0) out[0] = (wsum[0] + wsum[1] + wsum[2] + wsum[3]) / 128.0f;
}

extern "C" void kernel_launch(void* const* d_in, const int* in_sizes, int n_in,
                              void* d_out, int out_size, void* d_ws, size_t ws_size,
                              hipStream_t stream) {
    const float* z = (const float*)d_in[1];       // semantic_embeddings
    const int* labels = (const int*)d_in[3];      // labels

    ushort* zn = (ushort*)d_ws;                                   // 16 MB bf16
    char* p = (char*)d_ws + (size_t)N_ROWS * DIM * 2;
    float* row_same = (float*)p;                 p += N_ROWS * sizeof(float);
    float* row_diff = (float*)p;                 p += N_ROWS * sizeof(float);
    float* cls_same = (float*)p;                 p += 256 * sizeof(float);
    float* cls_diff = (float*)p;                 p += 256 * sizeof(float);
    int*   cls_cnt  = (int*)p;

    // zero rows + class accumulators in one shot
    hipMemsetAsync(row_same, 0,
                   (2 * N_ROWS + 2 * 256) * sizeof(float) + 256 * sizeof(int),
                   stream);

    normalize_kernel<<<N_ROWS, 256, 0, stream>>>(z, zn);

    gram_kernel<<<NTILES, 256, 0, stream>>>(zn, labels, row_same, row_diff);

    class_sum_kernel<<<N_ROWS / 256, 256, 0, stream>>>(labels, row_same, row_diff,
                                                       cls_same, cls_diff, cls_cnt);
    final_kernel<<<1, 256, 0, stream>>>(cls_same, cls_diff, cls_cnt, (float*)d_out);
}

// Round 3
// 283.250 us; speedup vs baseline: 1.2592x; 1.0960x over previous
//
#include <hip/hip_runtime.h>
#include <hip/hip_bf16.h>
#include <stdint.h>

#define N_ROWS 8192
#define DIM 1024
#define NUM_CLS 200
#define NT 64              // 128-row tiles per dimension
#define NSUP 10            // upper-tri super-tiles of 16x16 tiles
#define GRID_BLOCKS (NSUP * 256)

typedef __attribute__((ext_vector_type(8))) short bf16x8;
typedef __attribute__((ext_vector_type(4))) float f32x4;

__device__ __forceinline__ ushort f2bf(float f) {
    __hip_bfloat16 h = __float2bfloat16(f);
    return *reinterpret_cast<ushort*>(&h);
}

// ---------- Kernel 1: row L2-normalize, cast to bf16 (wave per row) ----------
__global__ __launch_bounds__(256) void normalize_kernel(const float* __restrict__ z,
                                                        ushort* __restrict__ zn) {
    const int row = blockIdx.x * 4 + (threadIdx.x >> 6);
    const int lane = threadIdx.x & 63;
    const float4 v = reinterpret_cast<const float4*>(z + (size_t)row * DIM)[lane];
    float ss = v.x * v.x + v.y * v.y + v.z * v.z + v.w * v.w;
    #pragma unroll
    for (int off = 1; off < 64; off <<= 1) ss += __shfl_xor(ss, off);
    const float inv = 1.0f / fmaxf(sqrtf(ss), 1e-8f);
    ushort4 o;
    o.x = f2bf(v.x * inv);
    o.y = f2bf(v.y * inv);
    o.z = f2bf(v.z * inv);
    o.w = f2bf(v.w * inv);
    reinterpret_cast<ushort4*>(zn + (size_t)row * DIM)[lane] = o;
}

// ---------- Kernel 2: fused Gram + exp + masked row sums, symmetric ----------
// Block remap: 10 super-tiles (16x16 tiles each = 256 blocks). Within a
// super-tile, round-robin dispatch (blk->XCD = blk%8) gives each XCD a 4x8
// tile slab: A 1MB + B 2MB = 3MB, fits the 4MB per-XCD L2. Diagonal
// super-tiles early-exit their 120 lower-triangle slots.
__global__ __launch_bounds__(256) void gram_kernel(const ushort* __restrict__ zn,
                                                   const int* __restrict__ labels,
                                                   float* __restrict__ row_same,
                                                   float* __restrict__ row_diff) {
    // super-tile order shares the A row-band between consecutive super-tiles
    constexpr int SBi[NSUP] = {0, 0, 0, 0, 1, 1, 1, 2, 2, 3};
    constexpr int SBj[NSUP] = {0, 1, 2, 3, 1, 2, 3, 2, 3, 3};

    const int st = blockIdx.x >> 8;       // 0..9
    const int p = blockIdx.x & 255;
    const int xcd = p & 7;                // round-robin XCD slot
    const int idx = p >> 3;               // 0..31 within slab
    const int bi_local = (xcd >> 1) * 4 + (idx >> 3);   // 0..15
    const int bj_local = (xcd & 1) * 8 + (idx & 7);     // 0..15
    const int bi = SBi[st] * 16 + bi_local;
    const int bj = SBj[st] * 16 + bj_local;
    if (bi > bj) return;                  // block-uniform, before any sync
    const bool diag = (bi == bj);

    __shared__ ushort sA[128 * 64];
    __shared__ ushort sB[128 * 64];
    __shared__ int labR[128], labC[128];

    const int r0 = bi * 128, c0 = bj * 128;
    const int t = threadIdx.x;
    const int lane = t & 63, wv = t >> 6;
    const int wr = wv >> 1, wc = wv & 1;

    if (t < 128) labR[t] = labels[r0 + t];
    else labC[t - 128] = labels[c0 + (t - 128)];

    f32x4 acc[4][4];
    #pragma unroll
    for (int m = 0; m < 4; m++)
        #pragma unroll
        for (int n = 0; n < 4; n++) acc[m][n] = (f32x4){0.f, 0.f, 0.f, 0.f};

    const int lrow = lane >> 3;  // 0..7 rows within a 1KB stage chunk
    const int lcol = lane & 7;   // 0..7 chunks of 8 bf16 (16B)

    for (int kt = 0; kt < DIM; kt += 64) {
        #pragma unroll
        for (int c = 0; c < 4; c++) {
            const int rowT = wv * 32 + c * 8 + lrow;
            const ushort* gA = zn + (size_t)(r0 + rowT) * DIM + kt + lcol * 8;
            __builtin_amdgcn_global_load_lds(
                (const __attribute__((address_space(1))) uint32_t*)gA,
                (__attribute__((address_space(3))) uint32_t*)&sA[rowT * 64 + lcol * 8],
                16, 0, 0);
            const ushort* gB = zn + (size_t)(c0 + rowT) * DIM + kt + lcol * 8;
            __builtin_amdgcn_global_load_lds(
                (const __attribute__((address_space(1))) uint32_t*)gB,
                (__attribute__((address_space(3))) uint32_t*)&sB[rowT * 64 + lcol * 8],
                16, 0, 0);
        }
        __syncthreads();
        #pragma unroll
        for (int ks = 0; ks < 2; ks++) {
            const int kof = ks * 32 + (lane >> 4) * 8;
            bf16x8 af[4], bfr[4];
            #pragma unroll
            for (int m = 0; m < 4; m++)
                af[m] = *reinterpret_cast<const bf16x8*>(
                    &sA[(wr * 64 + m * 16 + (lane & 15)) * 64 + kof]);
            #pragma unroll
            for (int n = 0; n < 4; n++)
                bfr[n] = *reinterpret_cast<const bf16x8*>(
                    &sB[(wc * 64 + n * 16 + (lane & 15)) * 64 + kof]);
            #pragma unroll
            for (int m = 0; m < 4; m++)
                #pragma unroll
                for (int n = 0; n < 4; n++)
                    acc[m][n] = __builtin_amdgcn_mfma_f32_16x16x32_bf16(
                        af[m], bfr[n], acc[m][n], 0, 0, 0);
        }
        __syncthreads();
    }

    // Epilogue. C/D layout: col = lane&15, row = (lane>>4)*4 + q  [m89]
    float rs[4][4], rd[4][4];   // per (m,q): row partial sums
    float cs[4], cd[4];         // per n: column partial sums (off-diag only)
    #pragma unroll
    for (int m = 0; m < 4; m++)
        #pragma unroll
        for (int q = 0; q < 4; q++) { rs[m][q] = 0.f; rd[m][q] = 0.f; }

    #pragma unroll
    for (int n = 0; n < 4; n++) {
        const int jj = wc * 64 + n * 16 + (lane & 15);
        const int j = c0 + jj;
        const int lj = labC[jj];
        float csn = 0.f, cdn = 0.f;
        #pragma unroll
        for (int m = 0; m < 4; m++) {
            #pragma unroll
            for (int q = 0; q < 4; q++) {
                const int ii = wr * 64 + m * 16 + (lane >> 4) * 4 + q;
                const float e = __expf(acc[m][n][q]);
                const bool same = (labR[ii] == lj);
                if (diag) {
                    if (r0 + ii != j) {
                        if (same) rs[m][q] += e; else rd[m][q] += e;
                    }
                } else {
                    if (same) { rs[m][q] += e; csn += e; }
                    else      { rd[m][q] += e; cdn += e; }
                }
            }
        }
        cs[n] = csn; cd[n] = cdn;
    }

    // Row reduction: across the 16 lanes sharing an output row.
    #pragma unroll
    for (int m = 0; m < 4; m++) {
        #pragma unroll
        for (int q = 0; q < 4; q++) {
            float vs = rs[m][q], vd = rd[m][q];
            #pragma unroll
            for (int off = 1; off < 16; off <<= 1) {
                vs += __shfl_xor(vs, off);
                vd += __shfl_xor(vd, off);
            }
            if ((lane & 15) == 0) {
                const int i = r0 + wr * 64 + m * 16 + (lane >> 4) * 4 + q;
                atomicAdd(&row_same[i], vs);
                atomicAdd(&row_diff[i], vd);
            }
        }
    }

    // Column reduction (symmetry contribution), off-diagonal tiles only.
    if (!diag) {
        #pragma unroll
        for (int n = 0; n < 4; n++) {
            float vs = cs[n], vd = cd[n];
            vs += __shfl_xor(vs, 16); vd += __shfl_xor(vd, 16);
            vs += __shfl_xor(vs, 32); vd += __shfl_xor(vd, 32);
            if (lane < 16) {
                const int j = c0 + wc * 64 + n * 16 + lane;
                atomicAdd(&row_same[j], vs);
                atomicAdd(&row_diff[j], vd);
            }
        }
    }
}

// ---------- Kernel 3a: per-block class partial sums ----------
__global__ __launch_bounds__(256) void class_sum_kernel(const int* __restrict__ labels,
                                                        const float* __restrict__ row_same,
                                                        const float* __restrict__ row_diff,
                                                        float* __restrict__ cls_same,
                                                        float* __restrict__ cls_diff,
                                                        int* __restrict__ cls_cnt) {
    __shared__ float ls[NUM_CLS], ld_[NUM_CLS];
    __shared__ int lc[NUM_CLS];
    const int t = threadIdx.x;
    for (int c = t; c < NUM_CLS; c += 256) { ls[c] = 0.f; ld_[c] = 0.f; lc[c] = 0; }
    __syncthreads();
    const int r = blockIdx.x * 256 + t;
    if (r < N_ROWS) {
        const int l = labels[r];
        atomicAdd(&ls[l], row_same[r]);
        atomicAdd(&ld_[l], row_diff[r]);
        atomicAdd(&lc[l], 1);
    }
    __syncthreads();
    for (int c = t; c < NUM_CLS; c += 256) {
        if (lc[c] > 0) {
            atomicAdd(&cls_same[c], ls[c]);
            atomicAdd(&cls_diff[c], ld_[c]);
            atomicAdd(&cls_cnt[c], lc[c]);
        }
    }
}

// ---------- Kernel 3b: final scalar ----------
__global__ __launch_bounds__(256) void final_kernel(const float* __restrict__ cls_same,
                                                    const float* __restrict__ cls_diff,
                                                    const int* __restrict__ cls_cnt,
                                                    float* __restrict__ out) {
    const int t = threadIdx.x;
    float p = 0.f;
    if (t < NUM_CLS && cls_cnt[t] > 0) p = logf(cls_same[t] / cls_diff[t]);
    #pragma unroll
    for (int off = 1; off < 64; off <<= 1) p += __shfl_xor(p, off);
    __shared__ float wsum[4];
    if ((t & 63) == 0) wsum[t >> 6] = p;
    __syncthreads();
    if (t == 0) out[0] = (wsum[0] + wsum[1] + wsum[2] + wsum[3]) / 128.0f;
}

extern "C" void kernel_launch(void* const* d_in, const int* in_sizes, int n_in,
                              void* d_out, int out_size, void* d_ws, size_t ws_size,
                              hipStream_t stream) {
    const float* z = (const float*)d_in[1];       // semantic_embeddings
    const int* labels = (const int*)d_in[3];      // labels

    ushort* zn = (ushort*)d_ws;                                   // 16 MB bf16
    char* p = (char*)d_ws + (size_t)N_ROWS * DIM * 2;
    float* row_same = (float*)p;                 p += N_ROWS * sizeof(float);
    float* row_diff = (float*)p;                 p += N_ROWS * sizeof(float);
    float* cls_same = (float*)p;                 p += 256 * sizeof(float);
    float* cls_diff = (float*)p;                 p += 256 * sizeof(float);
    int*   cls_cnt  = (int*)p;

    hipMemsetAsync(row_same, 0,
                   (2 * N_ROWS + 2 * 256) * sizeof(float) + 256 * sizeof(int),
                   stream);

    normalize_kernel<<<N_ROWS / 4, 256, 0, stream>>>(z, zn);

    gram_kernel<<<GRID_BLOCKS, 256, 0, stream>>>(zn, labels, row_same, row_diff);

    class_sum_kernel<<<N_ROWS / 256, 256, 0, stream>>>(labels, row_same, row_diff,
                                                       cls_same, cls_diff, cls_cnt);
    final_kernel<<<1, 256, 0, stream>>>(cls_same, cls_diff, cls_cnt, (float*)d_out);
}

// Round 4
// 266.831 us; speedup vs baseline: 1.3367x; 1.0615x over previous
//
#include <hip/hip_runtime.h>
#include <hip/hip_bf16.h>
#include <stdint.h>

#define N_ROWS 8192
#define DIM 1024
#define NUM_CLS 200
#define BM 256             // square tile edge
#define BK 32              // K-step
#define NT2 32             // 256-tiles per dimension
#define NSUP 10            // upper-tri supertiles of 8x8 tiles
#define GRID_BLOCKS (NSUP * 64)

typedef __attribute__((ext_vector_type(8))) short bf16x8;
typedef __attribute__((ext_vector_type(4))) float f32x4;

__device__ __forceinline__ ushort f2bf(float f) {
    __hip_bfloat16 h = __float2bfloat16(f);
    return *reinterpret_cast<ushort*>(&h);
}

// ---------- Kernel 1: row L2-normalize, cast to bf16 (wave per row) ----------
__global__ __launch_bounds__(256) void normalize_kernel(const float* __restrict__ z,
                                                        ushort* __restrict__ zn) {
    const int row = blockIdx.x * 4 + (threadIdx.x >> 6);
    const int lane = threadIdx.x & 63;
    const float4 v = reinterpret_cast<const float4*>(z + (size_t)row * DIM)[lane];
    float ss = v.x * v.x + v.y * v.y + v.z * v.z + v.w * v.w;
    #pragma unroll
    for (int off = 1; off < 64; off <<= 1) ss += __shfl_xor(ss, off);
    const float inv = 1.0f / fmaxf(sqrtf(ss), 1e-8f);
    ushort4 o;
    o.x = f2bf(v.x * inv);
    o.y = f2bf(v.y * inv);
    o.z = f2bf(v.z * inv);
    o.w = f2bf(v.w * inv);
    reinterpret_cast<ushort4*>(zn + (size_t)row * DIM)[lane] = o;
}

// ---------- Kernel 2: fused Gram + exp + masked row sums ----------
// 256x256 tile, 8 waves (2x4), BK=32, double-buffered 64KB LDS,
// stage-first single-barrier K-loop, swizzled LDS (2-way conflicts),
// setprio around MFMA clusters. Upper-triangular via 8x8-tile supertiles.
__global__ __launch_bounds__(512, 1) void gram_kernel(const ushort* __restrict__ zn,
                                                      const int* __restrict__ labels,
                                                      float* __restrict__ row_same,
                                                      float* __restrict__ row_diff) {
    // supertile order: upper-tri column-major (diag supertiles spread out)
    constexpr int SBi[NSUP] = {0, 0, 1, 0, 1, 2, 0, 1, 2, 3};
    constexpr int SBj[NSUP] = {0, 1, 1, 2, 2, 2, 3, 3, 3, 3};

    const int st = blockIdx.x >> 6;      // 0..9
    const int p = blockIdx.x & 63;
    const int xcd = p & 7;               // round-robin XCD slot
    const int idx = p >> 3;              // 0..7 within slab
    const int bi_l = (xcd & 3) * 2 + (idx >> 2);   // 0..7
    const int bj_l = (xcd >> 2) * 4 + (idx & 3);   // 0..7
    const int bi = SBi[st] * 8 + bi_l;
    const int bj = SBj[st] * 8 + bj_l;
    if (bi > bj) return;                 // block-uniform, before any sync
    const bool diag = (bi == bj);

    const int r0 = bi * BM, c0 = bj * BM;
    const int t = threadIdx.x;
    const int lane = t & 63, wv = t >> 6;   // 8 waves
    const int wr = wv >> 2, wc = wv & 3;    // 2 x 4 wave grid

    __shared__ ushort sA[2][BM * BK];    // 2 x 16 KB
    __shared__ ushort sB[2][BM * BK];    // 2 x 16 KB  (total 64 KB)

    f32x4 acc[8][4];
    #pragma unroll
    for (int m = 0; m < 8; m++)
        #pragma unroll
        for (int n = 0; n < 4; n++) acc[m][n] = (f32x4){0.f, 0.f, 0.f, 0.f};

    // Stage one BK-slice of A and B into buffer `buf`.
    // LDS dest is linear (chunk c = 16B); global source slot is
    // inverse-swizzled: LDS slot s' holds global slot s = (s' - rr) & 3,
    // rr = (r + (r>>2)) & 3.  Reader applies s' = (s + rr) & 3.
    auto stage = [&](int buf, int kt) {
        #pragma unroll
        for (int h = 0; h < 2; h++) {
            const int c = h * 512 + t;          // 0..1023 chunks of 16B
            const int r = c >> 2;               // row 0..255
            const int sp = c & 3;               // LDS slot
            const int rr = (r + (r >> 2)) & 3;
            const int s = (sp - rr) & 3;        // global slot
            const ushort* gA = zn + (size_t)(r0 + r) * DIM + kt + s * 8;
            __builtin_amdgcn_global_load_lds(
                (const __attribute__((address_space(1))) uint32_t*)gA,
                (__attribute__((address_space(3))) uint32_t*)&sA[buf][c * 8],
                16, 0, 0);
            const ushort* gB = zn + (size_t)(c0 + r) * DIM + kt + s * 8;
            __builtin_amdgcn_global_load_lds(
                (const __attribute__((address_space(1))) uint32_t*)gB,
                (__attribute__((address_space(3))) uint32_t*)&sB[buf][c * 8],
                16, 0, 0);
        }
    };

    stage(0, 0);
    __syncthreads();

    int cur = 0;
    const int rbase = wr * 128 + (lane & 15);
    const int cbase = wc * 64 + (lane & 15);
    const int sidx = lane >> 4;              // k-slot 0..3

    for (int it = 0; it < DIM / BK; ++it) {
        if (it < DIM / BK - 1) stage(cur ^ 1, (it + 1) * BK);

        bf16x8 a[4], b[4];
        // phase 1: A rows m=0..3 + all B frags
        #pragma unroll
        for (int x = 0; x < 4; x++) {
            const int row = rbase + x * 16;
            const int sp = (sidx + row + (row >> 2)) & 3;
            a[x] = *reinterpret_cast<const bf16x8*>(&sA[cur][row * 32 + sp * 8]);
            const int rowb = cbase + x * 16;
            const int spb = (sidx + rowb + (rowb >> 2)) & 3;
            b[x] = *reinterpret_cast<const bf16x8*>(&sB[cur][rowb * 32 + spb * 8]);
        }
        __builtin_amdgcn_s_setprio(1);
        #pragma unroll
        for (int m = 0; m < 4; m++)
            #pragma unroll
            for (int n = 0; n < 4; n++)
                acc[m][n] = __builtin_amdgcn_mfma_f32_16x16x32_bf16(
                    a[m], b[n], acc[m][n], 0, 0, 0);
        __builtin_amdgcn_s_setprio(0);

        // phase 2: A rows m=4..7 (reuse B)
        #pragma unroll
        for (int x = 0; x < 4; x++) {
            const int row = rbase + (x + 4) * 16;
            const int sp = (sidx + row + (row >> 2)) & 3;
            a[x] = *reinterpret_cast<const bf16x8*>(&sA[cur][row * 32 + sp * 8]);
        }
        __builtin_amdgcn_s_setprio(1);
        #pragma unroll
        for (int m = 0; m < 4; m++)
            #pragma unroll
            for (int n = 0; n < 4; n++)
                acc[m + 4][n] = __builtin_amdgcn_mfma_f32_16x16x32_bf16(
                    a[m], b[n], acc[m + 4][n], 0, 0, 0);
        __builtin_amdgcn_s_setprio(0);

        __syncthreads();   // implicit vmcnt(0): next tile landed; buffers safe
        cur ^= 1;
    }

    // ---- labels into reused LDS ----
    int* labR = (int*)&sA[0][0];
    int* labC = labR + 256;
    if (t < 256) labR[t] = labels[r0 + t];
    else labC[t - 256] = labels[c0 + (t - 256)];
    __syncthreads();

    // ---- Epilogue: exp + masked sums. C/D: col=lane&15, row=(lane>>4)*4+q ----
    float cs[4] = {0.f, 0.f, 0.f, 0.f}, cd[4] = {0.f, 0.f, 0.f, 0.f};
    #pragma unroll
    for (int m = 0; m < 8; m++) {
        #pragma unroll
        for (int q = 0; q < 4; q++) {
            const int ii = wr * 128 + m * 16 + (lane >> 4) * 4 + q;
            const int li = labR[ii];
            float vs = 0.f, vd = 0.f;
            #pragma unroll
            for (int n = 0; n < 4; n++) {
                const int jj = wc * 64 + n * 16 + (lane & 15);
                const float e = __expf(acc[m][n][q]);
                const bool same = (li == labC[jj]);
                if (!diag || ii != jj) {
                    if (same) { vs += e; if (!diag) cs[n] += e; }
                    else      { vd += e; if (!diag) cd[n] += e; }
                }
            }
            // row reduce across the 16 lanes sharing this output row
            #pragma unroll
            for (int off = 1; off < 16; off <<= 1) {
                vs += __shfl_xor(vs, off);
                vd += __shfl_xor(vd, off);
            }
            if ((lane & 15) == 0) {
                atomicAdd(&row_same[r0 + ii], vs);
                atomicAdd(&row_diff[r0 + ii], vd);
            }
        }
    }

    // column sums (symmetry contribution), off-diagonal tiles only
    if (!diag) {
        #pragma unroll
        for (int n = 0; n < 4; n++) {
            float vs = cs[n], vd = cd[n];
            vs += __shfl_xor(vs, 16); vd += __shfl_xor(vd, 16);
            vs += __shfl_xor(vs, 32); vd += __shfl_xor(vd, 32);
            if (lane < 16) {
                const int j = c0 + wc * 64 + n * 16 + lane;
                atomicAdd(&row_same[j], vs);
                atomicAdd(&row_diff[j], vd);
            }
        }
    }
}

// ---------- Kernel 3a: per-block class partial sums ----------
__global__ __launch_bounds__(256) void class_sum_kernel(const int* __restrict__ labels,
                                                        const float* __restrict__ row_same,
                                                        const float* __restrict__ row_diff,
                                                        float* __restrict__ cls_same,
                                                        float* __restrict__ cls_diff,
                                                        int* __restrict__ cls_cnt) {
    __shared__ float ls[NUM_CLS], ld_[NUM_CLS];
    __shared__ int lc[NUM_CLS];
    const int t = threadIdx.x;
    for (int c = t; c < NUM_CLS; c += 256) { ls[c] = 0.f; ld_[c] = 0.f; lc[c] = 0; }
    __syncthreads();
    const int r = blockIdx.x * 256 + t;
    if (r < N_ROWS) {
        const int l = labels[r];
        atomicAdd(&ls[l], row_same[r]);
        atomicAdd(&ld_[l], row_diff[r]);
        atomicAdd(&lc[l], 1);
    }
    __syncthreads();
    for (int c = t; c < NUM_CLS; c += 256) {
        if (lc[c] > 0) {
            atomicAdd(&cls_same[c], ls[c]);
            atomicAdd(&cls_diff[c], ld_[c]);
            atomicAdd(&cls_cnt[c], lc[c]);
        }
    }
}

// ---------- Kernel 3b: final scalar ----------
__global__ __launch_bounds__(256) void final_kernel(const float* __restrict__ cls_same,
                                                    const float* __restrict__ cls_diff,
                                                    const int* __restrict__ cls_cnt,
                                                    float* __restrict__ out) {
    const int t = threadIdx.x;
    float p = 0.f;
    if (t < NUM_CLS && cls_cnt[t] > 0) p = logf(cls_same[t] / cls_diff[t]);
    #pragma unroll
    for (int off = 1; off < 64; off <<= 1) p += __shfl_xor(p, off);
    __shared__ float wsum[4];
    if ((t & 63) == 0) wsum[t >> 6] = p;
    __syncthreads();
    if (t == 0) out[0] = (wsum[0] + wsum[1] + wsum[2] + wsum[3]) / 128.0f;
}

extern "C" void kernel_launch(void* const* d_in, const int* in_sizes, int n_in,
                              void* d_out, int out_size, void* d_ws, size_t ws_size,
                              hipStream_t stream) {
    const float* z = (const float*)d_in[1];       // semantic_embeddings
    const int* labels = (const int*)d_in[3];      // labels

    ushort* zn = (ushort*)d_ws;                                   // 16 MB bf16
    char* p = (char*)d_ws + (size_t)N_ROWS * DIM * 2;
    float* row_same = (float*)p;                 p += N_ROWS * sizeof(float);
    float* row_diff = (float*)p;                 p += N_ROWS * sizeof(float);
    float* cls_same = (float*)p;                 p += 256 * sizeof(float);
    float* cls_diff = (float*)p;                 p += 256 * sizeof(float);
    int*   cls_cnt  = (int*)p;

    hipMemsetAsync(row_same, 0,
                   (2 * N_ROWS + 2 * 256) * sizeof(float) + 256 * sizeof(int),
                   stream);

    normalize_kernel<<<N_ROWS / 4, 256, 0, stream>>>(z, zn);

    gram_kernel<<<GRID_BLOCKS, 512, 0, stream>>>(zn, labels, row_same, row_diff);

    class_sum_kernel<<<N_ROWS / 256, 256, 0, stream>>>(labels, row_same, row_diff,
                                                       cls_same, cls_diff, cls_cnt);
    final_kernel<<<1, 256, 0, stream>>>(cls_same, cls_diff, cls_cnt, (float*)d_out);
}